// Round 16
// baseline (243.526 us; speedup 1.0000x reference)
//
#include <hip/hip_runtime.h>
#include <math.h>

#define B_ 8192
#define D_ 4096
#define K_ 64
#define EPSF 1e-8f
#define LN2F 0.69314718056f
#define SPLITS 16    // gather splits per class
#define ECH 1024     // entropy chunks per mask (128KB each)

typedef float f32x4 __attribute__((ext_vector_type(4)));
typedef unsigned short u16x4 __attribute__((ext_vector_type(4)));

__device__ __forceinline__ unsigned short f2bf(float f) {
  unsigned int b = __float_as_uint(f);
  b += 0x7FFF + ((b >> 16) & 1);  // round-to-nearest-even
  return (unsigned short)(b >> 16);
}

// ---------------- kernels ----------------

// zero counts[64] + sd1[64] + sd8[64] (contiguous 192 words)
__global__ void k_init(int* __restrict__ z) {
  if (threadIdx.x < 192) z[threadIdx.x] = 0;
}

// one wave per row; K_ == 64 == wavefront: one coalesced read + ballot
__global__ void k_labels(const float* __restrict__ probs, int* __restrict__ labels,
                         int* __restrict__ counts, int* __restrict__ rowlist) {
  int row = blockIdx.x * 4 + (threadIdx.x >> 6);
  int lane = threadIdx.x & 63;
  float p = probs[(size_t)row * K_ + lane];
  unsigned long long m = __ballot(p > 0.5f);
  if (lane == 0) {
    int k = __ffsll(m) - 1;
    labels[row] = (k >= 0) ? k : 0;
    if (k >= 0) {
      int pos = atomicAdd(&counts[k], 1);
      rowlist[k * B_ + pos] = row;
    }
  }
}

// block per row (proven ~6.4 TB/s shape): reduce ||a||^2, w=1/max(norm,eps);
// write bf16(w*a) copy (stores are fire-and-forget); sd atomic per block.
__global__ __launch_bounds__(256) void k_normcvt(const float* __restrict__ acts,
                                                 const int* __restrict__ labels,
                                                 unsigned short* __restrict__ bout,
                                                 float* __restrict__ sd) {
  __shared__ float lds[4];
  __shared__ float sw;
  int row = blockIdx.x;
  int t = threadIdx.x;
  const f32x4* rp = (const f32x4*)(acts + (size_t)row * D_);
  f32x4 v0 = rp[t];
  f32x4 v1 = rp[t + 256];
  f32x4 v2 = rp[t + 512];
  f32x4 v3 = rp[t + 768];
  float s = v0.x * v0.x + v0.y * v0.y + v0.z * v0.z + v0.w * v0.w;
  s += v1.x * v1.x + v1.y * v1.y + v1.z * v1.z + v1.w * v1.w;
  s += v2.x * v2.x + v2.y * v2.y + v2.z * v2.z + v2.w * v2.w;
  s += v3.x * v3.x + v3.y * v3.y + v3.z * v3.z + v3.w * v3.w;
#pragma unroll
  for (int o = 32; o > 0; o >>= 1) s += __shfl_down(s, o);
  if ((t & 63) == 0) lds[t >> 6] = s;
  __syncthreads();
  if (t == 0) {
    float stot = lds[0] + lds[1] + lds[2] + lds[3];
    float w = 1.0f / fmaxf(sqrtf(stot), EPSF);
    sw = w;
    atomicAdd(&sd[labels[row]], stot * w * w);
  }
  __syncthreads();
  float w = sw;
  unsigned short* brow = bout + (size_t)row * D_;
#define CVTSTORE(V, OFF)                                    \
  {                                                         \
    u16x4 u_;                                               \
    u_.x = f2bf(w * V.x);                                   \
    u_.y = f2bf(w * V.y);                                   \
    u_.z = f2bf(w * V.z);                                   \
    u_.w = f2bf(w * V.w);                                   \
    *(u16x4*)(brow + 4 * (OFF)) = u_;                       \
  }
  CVTSTORE(v0, t)
  CVTSTORE(v1, t + 256)
  CVTSTORE(v2, t + 512)
  CVTSTORE(v3, t + 768)
#undef CVTSTORE
}

__device__ __forceinline__ float ent1(float p) {
  p = fminf(fmaxf(p, EPSF), 1.0f - EPSF);
  float q = 1.0f - p;
  float lp = __builtin_amdgcn_logf(p);  // v_log_f32: log2
  float lq = __builtin_amdgcn_logf(fmaxf(q, 1e-38f));
  return -(p * lp + q * lq);
}

__device__ __forceinline__ float ent4(f32x4 v) {
  return ent1(v.x) + ent1(v.y) + ent1(v.z) + ent1(v.w);
}

#define GLOAD(X0, X1, ROW)                                        \
  {                                                               \
    const uint4* rp_ = (const uint4*)(bts + (size_t)(ROW)*D_);    \
    X0 = rp_[t];                                                  \
    X1 = rp_[t + 256];                                            \
  }

#define GCONS(X0, X1)                                             \
  {                                                               \
    unsigned int uu[8] = {X0.x, X0.y, X0.z, X0.w,                 \
                          X1.x, X1.y, X1.z, X1.w};                \
    _Pragma("unroll") for (int q = 0; q < 8; ++q) {               \
      acc[2 * q] += __uint_as_float(uu[q] << 16);                 \
      acc[2 * q + 1] += __uint_as_float(uu[q] & 0xFFFF0000u);     \
    }                                                             \
  }

// Fused: even blocks gather-classsum the L3-resident bf16 normalized copy
// (register accumulation, no norms work, half the bytes); odd blocks stream
// one 128KB mask chunk with NT loads (no L3 pollution -> bts stays resident).
__global__ __launch_bounds__(256) void k_fused(const unsigned short* __restrict__ bts,
                                               const f32x4* __restrict__ mask,
                                               const int* __restrict__ counts,
                                               const int* __restrict__ rowlist,
                                               float* __restrict__ Cpart,
                                               double* __restrict__ entp) {
  __shared__ float sh[4];
  int t = threadIdx.x;
  if (blockIdx.x & 1) {
    // ---- entropy: one 128KB chunk, NT ILP-8 ----
    int blk = blockIdx.x >> 1;  // 0..ECH-1
    const f32x4* base = mask + (size_t)blk * 8192;
    float s = 0.f;
#pragma unroll
    for (int o = 0; o < 4; ++o) {
      f32x4 v[8];
#pragma unroll
      for (int j = 0; j < 8; ++j) v[j] = __builtin_nontemporal_load(&base[t + (o * 8 + j) * 256]);
#pragma unroll
      for (int j = 0; j < 8; ++j) s += ent4(v[j]);
    }
#pragma unroll
    for (int o = 32; o > 0; o >>= 1) s += __shfl_down(s, o);
    if ((t & 63) == 0) sh[t >> 6] = s;
    __syncthreads();
    if (t == 0) entp[blk] = (double)((sh[0] + sh[1] + sh[2] + sh[3]) * LN2F);
  } else {
    // ---- gather classsum on bf16 rows (8KB each), register accumulation ----
    int g = blockIdx.x >> 1;  // 0..1023
    int k = g & 63;
    int split = g >> 6;  // 0..15
    int cnt = counts[k];
    int beg = (cnt * split) / SPLITS;
    int end = (cnt * (split + 1)) / SPLITS;
    const int* rl = rowlist + k * B_;
    float acc[16];
#pragma unroll
    for (int j = 0; j < 16; ++j) acc[j] = 0.f;
    uint4 a0, a1, b0, b1;
    int r = beg;
    if (end > beg) {
      GLOAD(a0, a1, rl[r]);
      for (; r + 2 <= end; r += 2) {
        GLOAD(b0, b1, rl[r + 1]);
        GCONS(a0, a1);
        if (r + 2 < end) GLOAD(a0, a1, rl[r + 2]);
        GCONS(b0, b1);
      }
      if (r < end) GCONS(a0, a1);
    }
    // acc[j] -> col 8t+j (j<8), col 2048+8t+(j-8) (j>=8)
    float* cp = Cpart + ((size_t)split * K_ + k) * D_;
    *(f32x4*)(cp + 8 * t) = *(f32x4*)&acc[0];
    *(f32x4*)(cp + 8 * t + 4) = *(f32x4*)&acc[4];
    *(f32x4*)(cp + 2048 + 8 * t) = *(f32x4*)&acc[8];
    *(f32x4*)(cp + 2048 + 8 * t + 4) = *(f32x4*)&acc[12];
  }
}

// mSm partials: 512 blocks; b<256 -> tensor1, else tensor8. k=b>>2, quarter q=b&3.
__global__ __launch_bounds__(256) void k_msm(const float* __restrict__ Cpart1,
                                             const float* __restrict__ Cpart8,
                                             float* __restrict__ msp1,
                                             float* __restrict__ msp8) {
  __shared__ float lds[4];
  int b = blockIdx.x;
  const float* Cpart = (b < 256) ? Cpart1 : Cpart8;
  float* msp = (b < 256) ? msp1 : msp8;
  b &= 255;
  int k = b >> 2;
  int q = b & 3;
  int t = threadIdx.x;
  int col = q * 1024 + 4 * t;
  f32x4 c = 0.f;
#pragma unroll
  for (int s = 0; s < SPLITS; ++s)
    c += *(const f32x4*)(Cpart + ((size_t)s * K_ + k) * D_ + col);
  float sq = c.x * c.x + c.y * c.y + c.z * c.z + c.w * c.w;
#pragma unroll
  for (int o = 32; o > 0; o >>= 1) sq += __shfl_down(sq, o);
  if ((t & 63) == 0) lds[t >> 6] = sq;
  __syncthreads();
  if (t == 0) msp[blockIdx.x & 255] = lds[0] + lds[1] + lds[2] + lds[3];
}

__global__ void k_final(const double* __restrict__ entpart, const int* __restrict__ counts,
                        const float* __restrict__ sd1, const float* __restrict__ sd8,
                        const float* __restrict__ msp1, const float* __restrict__ msp8,
                        float* __restrict__ out) {
  __shared__ double dl[8];
  int t = threadIdx.x;
  double e1 = 0.0, e8 = 0.0;
  for (int i = t; i < ECH; i += 256) {
    e1 += entpart[i];
    e8 += entpart[ECH + i];
  }
#pragma unroll
  for (int o = 32; o > 0; o >>= 1) {
    e1 += __shfl_down(e1, o);
    e8 += __shfl_down(e8, o);
  }
  int wid = t >> 6;
  if ((t & 63) == 0) { dl[wid] = e1; dl[4 + wid] = e8; }
  __syncthreads();
  float pcm1 = 0.f, pcm8 = 0.f, valid = 0.f;
  if (t < K_) {
    float mSm1 = msp1[t * 4] + msp1[t * 4 + 1] + msp1[t * 4 + 2] + msp1[t * 4 + 3];
    float mSm8 = msp8[t * 4] + msp8[t * 4 + 1] + msp8[t * 4 + 2] + msp8[t * 4 + 3];
    float n = (float)counts[t];
    bool v = (n >= 2.0f);
    float np = fmaxf(0.5f * n * (n - 1.0f), 1.0f);
    valid = v ? 1.0f : 0.f;
    pcm1 = v ? 0.5f * (mSm1 - sd1[t]) / np : 0.f;
    pcm8 = v ? 0.5f * (mSm8 - sd8[t]) / np : 0.f;
  }
#pragma unroll
  for (int o = 32; o > 0; o >>= 1) {
    pcm1 += __shfl_down(pcm1, o);
    pcm8 += __shfl_down(pcm8, o);
    valid += __shfl_down(valid, o);
  }
  if (t == 0) {
    double etot1 = dl[0] + dl[1] + dl[2] + dl[3];
    double etot8 = dl[4] + dl[5] + dl[6] + dl[7];
    float sp1 = (float)(etot1 / (double)((long long)B_ * D_));
    float sp8 = (float)(etot8 / (double)((long long)B_ * D_));
    float cs1 = (valid > 0.f) ? pcm1 / fmaxf(valid, 1.0f) : 0.f;
    float cs8 = (valid > 0.f) ? pcm8 / fmaxf(valid, 1.0f) : 0.f;
    float sim1 = -cs1, sim8 = -cs8;
    out[0] = sim1 + sim8 + 0.001f * (sp1 + sp8);
    out[1] = sim1;
    out[2] = sim8;
    out[3] = sp1;
    out[4] = sp8;
  }
}

// ---------------- launcher ----------------
// ws layout (bytes):
//   0         : double entpart[2][1024]    16384
//   16384     : int    labels[B]           32768
//   49152     : int    counts[64]          256  \
//   49408     : float  sd1[64]             256   } zeroed together (192 words)
//   49664     : float  sd8[64]             256  /
//   49920     : float  msp1[256]           1024
//   50944     : float  msp8[256]           1024
//   65536     : int    rowlist[K][B]       2097152
//   2162688   : float  Cpart1[16][K][D]    16777216
//   18939904  : float  Cpart8[16][K][D]    16777216
//   35717120  : ushort b1[B][D]            67108864
//   102825984 : ushort b8[B][D]            67108864
//   total ~170 MB (ws_size observed ~539 MB)

extern "C" void kernel_launch(void* const* d_in, const int* in_sizes, int n_in,
                              void* d_out, int out_size, void* d_ws, size_t ws_size,
                              hipStream_t stream) {
  const float* probs = (const float*)d_in[0];
  const float* a1 = (const float*)d_in[1];
  const float* a8 = (const float*)d_in[2];
  const float* m1 = (const float*)d_in[3];
  const float* m8 = (const float*)d_in[4];
  float* out = (float*)d_out;
  char* ws = (char*)d_ws;

  double* entpart = (double*)(ws + 0);
  int* labels = (int*)(ws + 16384);
  int* counts = (int*)(ws + 49152);
  float* sd1 = (float*)(ws + 49408);
  float* sd8 = (float*)(ws + 49664);
  float* msp1 = (float*)(ws + 49920);
  float* msp8 = (float*)(ws + 50944);
  int* rowlist = (int*)(ws + 65536);
  float* Cpart1 = (float*)(ws + 2162688);
  float* Cpart8 = (float*)(ws + 18939904);
  unsigned short* b1 = (unsigned short*)(ws + 35717120);
  unsigned short* b8 = (unsigned short*)(ws + 102825984);

  k_init<<<1, 256, 0, stream>>>(counts);
  k_labels<<<B_ / 4, 256, 0, stream>>>(probs, labels, counts, rowlist);
  // tensor 1: f32 read once; bf16 normalized copy stays L3-hot for the gather,
  // which overlaps with the NT mask-entropy stream
  k_normcvt<<<B_, 256, 0, stream>>>(a1, labels, b1, sd1);
  k_fused<<<2 * ECH, 256, 0, stream>>>(b1, (const f32x4*)m1, counts, rowlist, Cpart1,
                                       entpart);
  // tensor 8
  k_normcvt<<<B_, 256, 0, stream>>>(a8, labels, b8, sd8);
  k_fused<<<2 * ECH, 256, 0, stream>>>(b8, (const f32x4*)m8, counts, rowlist, Cpart8,
                                       entpart + ECH);
  k_msm<<<512, 256, 0, stream>>>(Cpart1, Cpart8, msp1, msp8);
  k_final<<<1, 256, 0, stream>>>(entpart, counts, sd1, sd8, msp1, msp8, out);
}

// Round 17
// 171.588 us; speedup vs baseline: 1.4193x; 1.4193x over previous
//
#include <hip/hip_runtime.h>
#include <math.h>

#define B_ 8192
#define D_ 4096
#define K_ 64
#define EPSF 1e-8f
#define LN2F 0.69314718056f
#define SPLITS 16  // gather splits per class per tensor
#define ECH 1024   // entropy chunks per mask (128KB each)

typedef float f32x4 __attribute__((ext_vector_type(4)));

// ---------------- kernels ----------------

// zero counts[64] + sd1[64] + sd8[64] (contiguous 192 words)
__global__ void k_init(int* __restrict__ z) {
  if (threadIdx.x < 192) z[threadIdx.x] = 0;
}

// one wave per row; K_ == 64 == wavefront: one coalesced read + ballot
__global__ void k_labels(const float* __restrict__ probs, int* __restrict__ counts,
                         int* __restrict__ rowlist) {
  int row = blockIdx.x * 4 + (threadIdx.x >> 6);
  int lane = threadIdx.x & 63;
  float p = probs[(size_t)row * K_ + lane];
  unsigned long long m = __ballot(p > 0.5f);
  if (lane == 0) {
    int k = __ffsll(m) - 1;
    if (k >= 0) {
      int pos = atomicAdd(&counts[k], 1);
      rowlist[k * B_ + pos] = row;
    }
  }
}

__device__ __forceinline__ float ent1(float p) {
  p = fminf(fmaxf(p, EPSF), 1.0f - EPSF);
  float q = 1.0f - p;
  float lp = __builtin_amdgcn_logf(p);  // v_log_f32: log2
  float lq = __builtin_amdgcn_logf(fmaxf(q, 1e-38f));
  return -(p * lp + q * lq);
}

__device__ __forceinline__ float ent4(f32x4 v) {
  return ent1(v.x) + ent1(v.y) + ent1(v.z) + ent1(v.w);
}

// Single-pass fused kernel: block = (tensor, class, split) gathers ~8 rows
// (r7 4-wave split-row body, low VGPR) AND streams one 128KB mask chunk.
// Per iteration the 4 entropy loads are issued FIRST, then the 4 row loads;
// the entropy math then waits only on the older ent loads (vmcnt semantics),
// so ~320 VALU cycles of log2 work execute inside the row-load latency
// shadow of the SAME wave. Full occupancy; minimum 536MB total traffic.
__global__ __launch_bounds__(256) void k_fused(
    const float* __restrict__ a1, const float* __restrict__ a8,
    const f32x4* __restrict__ m1, const f32x4* __restrict__ m8,
    const int* __restrict__ counts, const int* __restrict__ rowlist,
    float* __restrict__ Cpart1, float* __restrict__ Cpart8, float* __restrict__ sd1,
    float* __restrict__ sd8, double* __restrict__ entpart) {
  __shared__ float sh[8];  // parity-buffered norm combine [2][4]
  int b = blockIdx.x;
  int tensor = b >> 10;
  int g = b & 1023;
  const float* a = tensor ? a8 : a1;
  const f32x4* mask = tensor ? m8 : m1;
  float* Cpart = tensor ? Cpart8 : Cpart1;
  float* sd = tensor ? sd8 : sd1;
  double* ep = entpart + tensor * ECH;
  int k = g & 63;
  int split = g >> 6;  // 0..15
  int t = threadIdx.x;
  int wave = t >> 6;
  int lane = t & 63;
  int cnt = counts[k];
  int beg = (cnt * split) / SPLITS;
  int end = (cnt * (split + 1)) / SPLITS;
  const int* rl = rowlist + k * B_;
  const f32x4* mbase = mask + (size_t)g * 8192;  // 128KB chunk

  f32x4 acc0 = 0.f, acc1 = 0.f, acc2 = 0.f, acc3 = 0.f;
  float sdacc = 0.f, entacc = 0.f;
  int nrows = end - beg;
  int iters = (nrows > 8) ? nrows : 8;
  int par = 0;
  for (int i = 0; i < iters; ++i, par ^= 1) {
    bool doEnt = (i < 8);
    bool doRow = (i < nrows);
    f32x4 e0, e1, e2, e3;
    if (doEnt) {  // issue ent loads FIRST (older in vmcnt queue)
      e0 = mbase[t + (4 * i + 0) * 256];
      e1 = mbase[t + (4 * i + 1) * 256];
      e2 = mbase[t + (4 * i + 2) * 256];
      e3 = mbase[t + (4 * i + 3) * 256];
    }
    f32x4 v0, v1, v2, v3;
    if (doRow) {  // row loads issued after; stay in flight during ent math
      int row = rl[beg + i];
      const f32x4* rp = (const f32x4*)(a + (size_t)row * D_) + (wave * 256 + lane);
      v0 = rp[0];
      v1 = rp[64];
      v2 = rp[128];
      v3 = rp[192];
    }
    if (doEnt) entacc += ent4(e0) + ent4(e1) + ent4(e2) + ent4(e3);
    if (doRow) {
      float s = v0.x * v0.x + v0.y * v0.y + v0.z * v0.z + v0.w * v0.w;
      s += v1.x * v1.x + v1.y * v1.y + v1.z * v1.z + v1.w * v1.w;
      s += v2.x * v2.x + v2.y * v2.y + v2.z * v2.z + v2.w * v2.w;
      s += v3.x * v3.x + v3.y * v3.y + v3.z * v3.z + v3.w * v3.w;
#pragma unroll
      for (int o = 32; o > 0; o >>= 1) s += __shfl_xor(s, o);
      if (lane == 0) sh[par * 4 + wave] = s;
      __syncthreads();
      float stot = sh[par * 4] + sh[par * 4 + 1] + sh[par * 4 + 2] + sh[par * 4 + 3];
      float w = 1.0f / fmaxf(sqrtf(stot), EPSF);
      acc0 += w * v0;
      acc1 += w * v1;
      acc2 += w * v2;
      acc3 += w * v3;
      if (t == 0) sdacc += stot * w * w;
    }
  }

  // writeback gather quarters
  float* cp = Cpart + ((size_t)split * K_ + k) * D_ + wave * 1024;
  *(f32x4*)(cp + 4 * lane) = acc0;
  *(f32x4*)(cp + 4 * (64 + lane)) = acc1;
  *(f32x4*)(cp + 4 * (128 + lane)) = acc2;
  *(f32x4*)(cp + 4 * (192 + lane)) = acc3;
  if (t == 0 && sdacc != 0.f) atomicAdd(&sd[k], sdacc);

  // block-reduce entropy partial
  __syncthreads();  // sh free
#pragma unroll
  for (int o = 32; o > 0; o >>= 1) entacc += __shfl_down(entacc, o);
  if (lane == 0) sh[wave] = entacc;
  __syncthreads();
  if (t == 0) ep[g] = (double)((sh[0] + sh[1] + sh[2] + sh[3]) * LN2F);
}

// mSm partials: 512 blocks; b<256 -> tensor1, else tensor8. k=b>>2, quarter q=b&3.
__global__ __launch_bounds__(256) void k_msm(const float* __restrict__ Cpart1,
                                             const float* __restrict__ Cpart8,
                                             float* __restrict__ msp1,
                                             float* __restrict__ msp8) {
  __shared__ float lds[4];
  int b = blockIdx.x;
  const float* Cpart = (b < 256) ? Cpart1 : Cpart8;
  float* msp = (b < 256) ? msp1 : msp8;
  b &= 255;
  int k = b >> 2;
  int q = b & 3;
  int t = threadIdx.x;
  int col = q * 1024 + 4 * t;
  f32x4 c = 0.f;
#pragma unroll
  for (int s = 0; s < SPLITS; ++s)
    c += *(const f32x4*)(Cpart + ((size_t)s * K_ + k) * D_ + col);
  float sq = c.x * c.x + c.y * c.y + c.z * c.z + c.w * c.w;
#pragma unroll
  for (int o = 32; o > 0; o >>= 1) sq += __shfl_down(sq, o);
  if ((t & 63) == 0) lds[t >> 6] = sq;
  __syncthreads();
  if (t == 0) msp[blockIdx.x & 255] = lds[0] + lds[1] + lds[2] + lds[3];
}

__global__ void k_final(const double* __restrict__ entpart, const int* __restrict__ counts,
                        const float* __restrict__ sd1, const float* __restrict__ sd8,
                        const float* __restrict__ msp1, const float* __restrict__ msp8,
                        float* __restrict__ out) {
  __shared__ double dl[8];
  int t = threadIdx.x;
  double e1 = 0.0, e8 = 0.0;
  for (int i = t; i < ECH; i += 256) {
    e1 += entpart[i];
    e8 += entpart[ECH + i];
  }
#pragma unroll
  for (int o = 32; o > 0; o >>= 1) {
    e1 += __shfl_down(e1, o);
    e8 += __shfl_down(e8, o);
  }
  int wid = t >> 6;
  if ((t & 63) == 0) { dl[wid] = e1; dl[4 + wid] = e8; }
  __syncthreads();
  float pcm1 = 0.f, pcm8 = 0.f, valid = 0.f;
  if (t < K_) {
    float mSm1 = msp1[t * 4] + msp1[t * 4 + 1] + msp1[t * 4 + 2] + msp1[t * 4 + 3];
    float mSm8 = msp8[t * 4] + msp8[t * 4 + 1] + msp8[t * 4 + 2] + msp8[t * 4 + 3];
    float n = (float)counts[t];
    bool v = (n >= 2.0f);
    float np = fmaxf(0.5f * n * (n - 1.0f), 1.0f);
    valid = v ? 1.0f : 0.f;
    pcm1 = v ? 0.5f * (mSm1 - sd1[t]) / np : 0.f;
    pcm8 = v ? 0.5f * (mSm8 - sd8[t]) / np : 0.f;
  }
#pragma unroll
  for (int o = 32; o > 0; o >>= 1) {
    pcm1 += __shfl_down(pcm1, o);
    pcm8 += __shfl_down(pcm8, o);
    valid += __shfl_down(valid, o);
  }
  if (t == 0) {
    double etot1 = dl[0] + dl[1] + dl[2] + dl[3];
    double etot8 = dl[4] + dl[5] + dl[6] + dl[7];
    float sp1 = (float)(etot1 / (double)((long long)B_ * D_));
    float sp8 = (float)(etot8 / (double)((long long)B_ * D_));
    float cs1 = (valid > 0.f) ? pcm1 / fmaxf(valid, 1.0f) : 0.f;
    float cs8 = (valid > 0.f) ? pcm8 / fmaxf(valid, 1.0f) : 0.f;
    float sim1 = -cs1, sim8 = -cs8;
    out[0] = sim1 + sim8 + 0.001f * (sp1 + sp8);
    out[1] = sim1;
    out[2] = sim8;
    out[3] = sp1;
    out[4] = sp8;
  }
}

// ---------------- launcher ----------------
// ws layout (bytes):
//   0        : double entpart[2][1024]   16384
//   16384    : int    counts[64]         256  \
//   16640    : float  sd1[64]            256   } zeroed together (192 words)
//   16896    : float  sd8[64]            256  /
//   17152    : float  msp1[256]          1024
//   18176    : float  msp8[256]          1024
//   32768    : int    rowlist[K][B]      2097152
//   2129920  : float  Cpart1[16][K][D]   16777216
//   18907136 : float  Cpart8[16][K][D]   16777216
//   total ~35.7 MB (ws_size observed ~539 MB)

extern "C" void kernel_launch(void* const* d_in, const int* in_sizes, int n_in,
                              void* d_out, int out_size, void* d_ws, size_t ws_size,
                              hipStream_t stream) {
  const float* probs = (const float*)d_in[0];
  const float* a1 = (const float*)d_in[1];
  const float* a8 = (const float*)d_in[2];
  const float* m1 = (const float*)d_in[3];
  const float* m8 = (const float*)d_in[4];
  float* out = (float*)d_out;
  char* ws = (char*)d_ws;

  double* entpart = (double*)(ws + 0);
  int* counts = (int*)(ws + 16384);
  float* sd1 = (float*)(ws + 16640);
  float* sd8 = (float*)(ws + 16896);
  float* msp1 = (float*)(ws + 17152);
  float* msp8 = (float*)(ws + 18176);
  int* rowlist = (int*)(ws + 32768);
  float* Cpart1 = (float*)(ws + 2129920);
  float* Cpart8 = (float*)(ws + 18907136);

  k_init<<<1, 256, 0, stream>>>(counts);
  k_labels<<<B_ / 4, 256, 0, stream>>>(probs, counts, rowlist);
  // single fused pass over all 536MB: gather classnorm + in-shadow entropy
  k_fused<<<2048, 256, 0, stream>>>(a1, a8, (const f32x4*)m1, (const f32x4*)m8, counts,
                                    rowlist, Cpart1, Cpart8, sd1, sd8, entpart);
  k_msm<<<512, 256, 0, stream>>>(Cpart1, Cpart8, msp1, msp8);
  k_final<<<1, 256, 0, stream>>>(entpart, counts, sd1, sd8, msp1, msp8, out);
}

// Round 18
// 169.568 us; speedup vs baseline: 1.4362x; 1.0119x over previous
//
#include <hip/hip_runtime.h>
#include <math.h>

#define B_ 8192
#define D_ 4096
#define K_ 64
#define EPSF 1e-8f
#define LN2F 0.69314718056f
#define SPLITS 16  // gather splits per class per tensor
#define ECH 1024   // entropy chunks per mask (128KB each)

typedef float f32x4 __attribute__((ext_vector_type(4)));

// ---------------- kernels ----------------

// zero counts[64] + sd1[64] + sd8[64] (contiguous 192 words)
__global__ void k_init(int* __restrict__ z) {
  if (threadIdx.x < 192) z[threadIdx.x] = 0;
}

// one wave per row; K_ == 64 == wavefront: one coalesced read + ballot
__global__ void k_labels(const float* __restrict__ probs, int* __restrict__ counts,
                         int* __restrict__ rowlist) {
  int row = blockIdx.x * 4 + (threadIdx.x >> 6);
  int lane = threadIdx.x & 63;
  float p = probs[(size_t)row * K_ + lane];
  unsigned long long m = __ballot(p > 0.5f);
  if (lane == 0) {
    int k = __ffsll(m) - 1;
    if (k >= 0) {
      int pos = atomicAdd(&counts[k], 1);
      rowlist[k * B_ + pos] = row;
    }
  }
}

__device__ __forceinline__ float ent1(float p) {
  p = fminf(fmaxf(p, EPSF), 1.0f - EPSF);
  float q = 1.0f - p;
  float lp = __builtin_amdgcn_logf(p);  // v_log_f32: log2
  float lq = __builtin_amdgcn_logf(fmaxf(q, 1e-38f));
  return -(p * lp + q * lq);
}

__device__ __forceinline__ float ent4(f32x4 v) {
  return ent1(v.x) + ent1(v.y) + ent1(v.z) + ent1(v.w);
}

// Fused kernel, XCD-mixed: consecutive blockIdx round-robins across the 8
// XCDs, so the task type is chosen by (blockIdx>>3)&1 — every XCD runs BOTH
// the backend-limited gather (which is insensitive to wave count) and the
// BW-limited entropy stream concurrently. Gather body: block per (tensor,
// class, split), 4 waves each own a 1024-col quarter, 2-row software
// pipeline (next row's loads issued before current row's reduce -> vmcnt
// waits only on older loads), parity-buffered LDS norm combine.
__global__ __launch_bounds__(256) void k_fused(
    const float* __restrict__ a1, const float* __restrict__ a8,
    const f32x4* __restrict__ m1, const f32x4* __restrict__ m8,
    const int* __restrict__ counts, const int* __restrict__ rowlist,
    float* __restrict__ Cpart1, float* __restrict__ Cpart8, float* __restrict__ sd1,
    float* __restrict__ sd8, double* __restrict__ entpart) {
  __shared__ float sh[8];  // parity-buffered norm combine [2][4]
  int b = blockIdx.x;
  int grp = b >> 3;
  int lane8 = b & 7;
  int type = grp & 1;
  int id = (grp >> 1) * 8 + lane8;  // 0..2047 within each type
  int t = threadIdx.x;

  if (type) {
    // ---- entropy: one 128KB chunk; id: mask = id>>10, chunk = id&1023 ----
    const f32x4* mbase = ((id >> 10) ? m8 : m1) + (size_t)(id & 1023) * 8192;
    double* ep = entpart + ((id >> 10) ? ECH : 0);
    float s = 0.f;
#pragma unroll
    for (int o = 0; o < 4; ++o) {
      f32x4 v[8];
#pragma unroll
      for (int j = 0; j < 8; ++j) v[j] = mbase[t + (o * 8 + j) * 256];
#pragma unroll
      for (int j = 0; j < 8; ++j) s += ent4(v[j]);
    }
#pragma unroll
    for (int o = 32; o > 0; o >>= 1) s += __shfl_down(s, o);
    if ((t & 63) == 0) sh[t >> 6] = s;
    __syncthreads();
    if (t == 0) ep[id & 1023] = (double)((sh[0] + sh[1] + sh[2] + sh[3]) * LN2F);
  } else {
    // ---- gather classnorm; id: tensor = id>>10, k = id&63, split = (id&1023)>>6 ----
    int tensor = id >> 10;
    const float* a = tensor ? a8 : a1;
    float* Cpart = tensor ? Cpart8 : Cpart1;
    float* sd = tensor ? sd8 : sd1;
    int k = id & 63;
    int split = (id & 1023) >> 6;  // 0..15
    int wave = t >> 6;
    int lane = t & 63;
    int cnt = counts[k];
    int beg = (cnt * split) / SPLITS;
    int end = (cnt * (split + 1)) / SPLITS;
    const int* rl = rowlist + k * B_;

    f32x4 acc0 = 0.f, acc1 = 0.f, acc2 = 0.f, acc3 = 0.f;
    float sdacc = 0.f;
    int nrows = end - beg;
    f32x4 va0, va1, va2, va3, vb0, vb1, vb2, vb3;
    int qoff = wave * 256 + lane;

#define LROW(X0, X1, X2, X3, RIDX)                                        \
    {                                                                     \
      const f32x4* rp_ = (const f32x4*)(a + (size_t)rl[RIDX] * D_) + qoff;\
      X0 = rp_[0];                                                        \
      X1 = rp_[64];                                                       \
      X2 = rp_[128];                                                      \
      X3 = rp_[192];                                                      \
    }
#define CROW(X0, X1, X2, X3, PAR)                                         \
    {                                                                     \
      float s_ = X0.x * X0.x + X0.y * X0.y + X0.z * X0.z + X0.w * X0.w;   \
      s_ += X1.x * X1.x + X1.y * X1.y + X1.z * X1.z + X1.w * X1.w;        \
      s_ += X2.x * X2.x + X2.y * X2.y + X2.z * X2.z + X2.w * X2.w;        \
      s_ += X3.x * X3.x + X3.y * X3.y + X3.z * X3.z + X3.w * X3.w;        \
      _Pragma("unroll") for (int o = 32; o > 0; o >>= 1)                  \
          s_ += __shfl_xor(s_, o);                                        \
      if (lane == 0) sh[(PAR)*4 + wave] = s_;                             \
      __syncthreads();                                                    \
      float st_ = sh[(PAR)*4] + sh[(PAR)*4 + 1] + sh[(PAR)*4 + 2] +       \
                  sh[(PAR)*4 + 3];                                        \
      float w_ = 1.0f / fmaxf(sqrtf(st_), EPSF);                          \
      acc0 += w_ * X0;                                                    \
      acc1 += w_ * X1;                                                    \
      acc2 += w_ * X2;                                                    \
      acc3 += w_ * X3;                                                    \
      if (t == 0) sdacc += st_ * w_ * w_;                                 \
    }

    if (nrows > 0) {
      LROW(va0, va1, va2, va3, beg)
      int i = 0;
      for (; i + 2 <= nrows; i += 2) {
        LROW(vb0, vb1, vb2, vb3, beg + i + 1)
        CROW(va0, va1, va2, va3, 0)
        if (i + 2 < nrows) LROW(va0, va1, va2, va3, beg + i + 2)
        CROW(vb0, vb1, vb2, vb3, 1)
      }
      if (i < nrows) CROW(va0, va1, va2, va3, 0)
    }
#undef LROW
#undef CROW

    float* cp = Cpart + ((size_t)split * K_ + k) * D_ + wave * 1024;
    *(f32x4*)(cp + 4 * lane) = acc0;
    *(f32x4*)(cp + 4 * (64 + lane)) = acc1;
    *(f32x4*)(cp + 4 * (128 + lane)) = acc2;
    *(f32x4*)(cp + 4 * (192 + lane)) = acc3;
    if (t == 0 && sdacc != 0.f) atomicAdd(&sd[k], sdacc);
  }
}

// mSm partials: 512 blocks; b<256 -> tensor1, else tensor8. k=b>>2, quarter q=b&3.
__global__ __launch_bounds__(256) void k_msm(const float* __restrict__ Cpart1,
                                             const float* __restrict__ Cpart8,
                                             float* __restrict__ msp1,
                                             float* __restrict__ msp8) {
  __shared__ float lds[4];
  int b = blockIdx.x;
  const float* Cpart = (b < 256) ? Cpart1 : Cpart8;
  float* msp = (b < 256) ? msp1 : msp8;
  b &= 255;
  int k = b >> 2;
  int q = b & 3;
  int t = threadIdx.x;
  int col = q * 1024 + 4 * t;
  f32x4 c = 0.f;
#pragma unroll
  for (int s = 0; s < SPLITS; ++s)
    c += *(const f32x4*)(Cpart + ((size_t)s * K_ + k) * D_ + col);
  float sq = c.x * c.x + c.y * c.y + c.z * c.z + c.w * c.w;
#pragma unroll
  for (int o = 32; o > 0; o >>= 1) sq += __shfl_down(sq, o);
  if ((t & 63) == 0) lds[t >> 6] = sq;
  __syncthreads();
  if (t == 0) msp[blockIdx.x & 255] = lds[0] + lds[1] + lds[2] + lds[3];
}

__global__ void k_final(const double* __restrict__ entpart, const int* __restrict__ counts,
                        const float* __restrict__ sd1, const float* __restrict__ sd8,
                        const float* __restrict__ msp1, const float* __restrict__ msp8,
                        float* __restrict__ out) {
  __shared__ double dl[8];
  int t = threadIdx.x;
  double e1 = 0.0, e8 = 0.0;
  for (int i = t; i < ECH; i += 256) {
    e1 += entpart[i];
    e8 += entpart[ECH + i];
  }
#pragma unroll
  for (int o = 32; o > 0; o >>= 1) {
    e1 += __shfl_down(e1, o);
    e8 += __shfl_down(e8, o);
  }
  int wid = t >> 6;
  if ((t & 63) == 0) { dl[wid] = e1; dl[4 + wid] = e8; }
  __syncthreads();
  float pcm1 = 0.f, pcm8 = 0.f, valid = 0.f;
  if (t < K_) {
    float mSm1 = msp1[t * 4] + msp1[t * 4 + 1] + msp1[t * 4 + 2] + msp1[t * 4 + 3];
    float mSm8 = msp8[t * 4] + msp8[t * 4 + 1] + msp8[t * 4 + 2] + msp8[t * 4 + 3];
    float n = (float)counts[t];
    bool v = (n >= 2.0f);
    float np = fmaxf(0.5f * n * (n - 1.0f), 1.0f);
    valid = v ? 1.0f : 0.f;
    pcm1 = v ? 0.5f * (mSm1 - sd1[t]) / np : 0.f;
    pcm8 = v ? 0.5f * (mSm8 - sd8[t]) / np : 0.f;
  }
#pragma unroll
  for (int o = 32; o > 0; o >>= 1) {
    pcm1 += __shfl_down(pcm1, o);
    pcm8 += __shfl_down(pcm8, o);
    valid += __shfl_down(valid, o);
  }
  if (t == 0) {
    double etot1 = dl[0] + dl[1] + dl[2] + dl[3];
    double etot8 = dl[4] + dl[5] + dl[6] + dl[7];
    float sp1 = (float)(etot1 / (double)((long long)B_ * D_));
    float sp8 = (float)(etot8 / (double)((long long)B_ * D_));
    float cs1 = (valid > 0.f) ? pcm1 / fmaxf(valid, 1.0f) : 0.f;
    float cs8 = (valid > 0.f) ? pcm8 / fmaxf(valid, 1.0f) : 0.f;
    float sim1 = -cs1, sim8 = -cs8;
    out[0] = sim1 + sim8 + 0.001f * (sp1 + sp8);
    out[1] = sim1;
    out[2] = sim8;
    out[3] = sp1;
    out[4] = sp8;
  }
}

// ---------------- launcher ----------------
// ws layout (bytes):
//   0        : double entpart[2][1024]   16384
//   16384    : int    counts[64]         256  \
//   16640    : float  sd1[64]            256   } zeroed together (192 words)
//   16896    : float  sd8[64]            256  /
//   17152    : float  msp1[256]          1024
//   18176    : float  msp8[256]          1024
//   32768    : int    rowlist[K][B]      2097152
//   2129920  : float  Cpart1[16][K][D]   16777216
//   18907136 : float  Cpart8[16][K][D]   16777216
//   total ~35.7 MB (ws_size observed ~539 MB)

extern "C" void kernel_launch(void* const* d_in, const int* in_sizes, int n_in,
                              void* d_out, int out_size, void* d_ws, size_t ws_size,
                              hipStream_t stream) {
  const float* probs = (const float*)d_in[0];
  const float* a1 = (const float*)d_in[1];
  const float* a8 = (const float*)d_in[2];
  const float* m1 = (const float*)d_in[3];
  const float* m8 = (const float*)d_in[4];
  float* out = (float*)d_out;
  char* ws = (char*)d_ws;

  double* entpart = (double*)(ws + 0);
  int* counts = (int*)(ws + 16384);
  float* sd1 = (float*)(ws + 16640);
  float* sd8 = (float*)(ws + 16896);
  float* msp1 = (float*)(ws + 17152);
  float* msp8 = (float*)(ws + 18176);
  int* rowlist = (int*)(ws + 32768);
  float* Cpart1 = (float*)(ws + 2129920);
  float* Cpart8 = (float*)(ws + 18907136);

  k_init<<<1, 256, 0, stream>>>(counts);
  k_labels<<<B_ / 4, 256, 0, stream>>>(probs, counts, rowlist);
  // single fused pass over all 536MB; gather and entropy mixed WITHIN each XCD
  k_fused<<<4096, 256, 0, stream>>>(a1, a8, (const f32x4*)m1, (const f32x4*)m8, counts,
                                    rowlist, Cpart1, Cpart8, sd1, sd8, entpart);
  k_msm<<<512, 256, 0, stream>>>(Cpart1, Cpart8, msp1, msp8);
  k_final<<<1, 256, 0, stream>>>(entpart, counts, sd1, sd8, msp1, msp8, out);
}